// Round 9
// baseline (690.031 us; speedup 1.0000x reference)
//
#include <hip/hip_runtime.h>
#include <math.h>

#define EPS 1e-7f
#define IN1_ELEMS 26214400   // 256*20*20*256 (fp16 elements, single plane)
#define BT_ELEMS  5308416    // 256*20736 (per fp16 plane)

typedef float fvec4 __attribute__((ext_vector_type(4)));
typedef short short8 __attribute__((ext_vector_type(8)));
typedef _Float16 half8 __attribute__((ext_vector_type(8)));

__device__ inline unsigned short f2h(float f){
  _Float16 h = (_Float16)f;
  return __builtin_bit_cast(unsigned short, h);
}
__device__ inline float h2f(unsigned short u){
  return (float)__builtin_bit_cast(_Float16, u);
}
__device__ inline void async16(unsigned short* dst, const unsigned short* src){
  __builtin_amdgcn_global_load_lds((const __attribute__((address_space(1))) void*)src,
                                   (__attribute__((address_space(3))) void*)dst, 16, 0, 0);
}
__device__ inline fvec4 mfma_f16(short8 a, short8 b, fvec4 c){
  return __builtin_amdgcn_mfma_f32_16x16x32_f16(
      __builtin_bit_cast(half8, a), __builtin_bit_cast(half8, b), c, 0, 0, 0);
}

// ---------------- K0: prep = wt (B split, x64) + conv1 (fp16 x 2^-6) + zeroing -------
// blocks [0,1296): weight transpose + zero c2out; blocks [1296,6416): conv1,
// first 320 of them also zero s1+s2.
__global__ __launch_bounds__(256) void prep_kernel(const float* __restrict__ w2,
    unsigned short* __restrict__ BTh, unsigned short* __restrict__ BTl,
    float* __restrict__ c2out,
    const float* __restrict__ img, const float* __restrict__ w1,
    const float* __restrict__ b1, unsigned short* __restrict__ outh,
    float* __restrict__ s1s2){
  const int bid = blockIdx.x;
  const int t = threadIdx.x;
  if (bid < 1296){
    __shared__ float tile[64][65];
    int k0 = (bid % 324) * 64, oc0 = (bid / 324) * 64;
    for (int g = bid*256 + t; g < 2359296; g += 1296*256) c2out[g] = 0.f;
    #pragma unroll
    for (int p = 0; p < 16; ++p){
      int f = p*256 + t;
      int kr = f >> 6, cc = f & 63;
      tile[kr][cc] = w2[(size_t)(k0 + kr)*256 + oc0 + cc];
    }
    __syncthreads();
    #pragma unroll
    for (int p = 0; p < 16; ++p){
      int f = p*256 + t;
      int ocr = f >> 6, kc = f & 63;
      float v = tile[kc][ocr] * 64.f;
      unsigned short h = f2h(v);
      size_t idx = (size_t)(oc0 + ocr)*20736 + k0 + kc;
      BTh[idx] = h;
      BTl[idx] = f2h(v - h2f(h));
    }
  } else {
    const int cid = bid - 1296;
    if (cid < 320) s1s2[cid*256 + t] = 0.f;
    __shared__ float sim[252];
    int oh = cid % 20, b = cid / 20;
    if (t < 252) sim[t] = img[((size_t)b*28 + oh + t/28)*28 + (t%28)];
    __syncthreads();
    float acc[20];
    #pragma unroll
    for (int i = 0; i < 20; ++i) acc[i] = 0.f;
    #pragma unroll
    for (int kh = 0; kh < 9; ++kh){
      float im[28];
      #pragma unroll
      for (int c = 0; c < 28; ++c) im[c] = sim[kh*28 + c];
      #pragma unroll
      for (int kw = 0; kw < 9; ++kw){
        float wv = w1[(kh*9 + kw)*256 + t];
        #pragma unroll
        for (int ow = 0; ow < 20; ++ow) acc[ow] = fmaf(im[ow + kw], wv, acc[ow]);
      }
    }
    float bv = b1[t];
    size_t base = ((size_t)(b*20 + oh))*20*256 + t;
    #pragma unroll
    for (int ow = 0; ow < 20; ++ow){
      float v = fmaxf(acc[ow] + bv, 0.f);
      outh[base + ow*256] = f2h(v * 0.015625f);   // x 2^-6
    }
  }
}

// ---------------- K2: conv2 implicit GEMM, fp16 2-pass MFMA (unchanged R7) -----------
__global__ __launch_bounds__(256) void conv2_mfma(const unsigned short* __restrict__ in1h,
    const unsigned short* __restrict__ BTh, float* __restrict__ out){
  __shared__ __align__(16) unsigned short lds[24576]; // 2 bufs x (A|Bh|Bl 4096 shorts)
  const int t = threadIdx.x;
  const int lane = t & 63, w = t >> 6;
  const int m0 = blockIdx.y * 128, n0 = blockIdx.x * 128;
  const int rowA = t >> 2, q = (t & 3) ^ ((t >> 3) & 3);

  const unsigned short* aS[2];
  const unsigned short* bS[2];
  #pragma unroll
  for (int h = 0; h < 2; ++h){
    int m = m0 + h*64 + rowA;
    int bb = m / 36, s = m - bb*36, oh = s / 6, ow = s - oh*6;
    aS[h] = in1h + ((size_t)((bb*20 + 2*oh)*20 + 2*ow))*256 + q*8;
    int n = n0 + h*64 + rowA;
    bS[h] = BTh + (size_t)n*20736 + q*8;
  }

  const int r = lane & 15;
  const int p = (lane >> 4) ^ ((lane >> 1) & 3);
  int roA[4], roB[4];
  #pragma unroll
  for (int i=0;i<4;++i){
    roA[i] = ((w >> 1)*64 + i*16 + r)*32 + p*8;
    roB[i] = ((w & 1)*64  + i*16 + r)*32 + p*8;
  }

  fvec4 acc[4][4];
  #pragma unroll
  for (int i=0;i<4;++i)
    #pragma unroll
    for (int j=0;j<4;++j) acc[i][j] = (fvec4){0.f,0.f,0.f,0.f};

  const int ks0 = blockIdx.z * 81;

  #define STAGE(BUF, KS) do{                                            \
    int kk_ = (KS) >> 3, kh_ = kk_/9, kw_ = kk_ - kh_*9;                \
    int aoff_ = (kh_*20 + kw_)*256 + ((KS) & 7)*32;                     \
    int boff_ = (KS)*32;                                                \
    int base_ = (BUF)*12288;                                            \
    _Pragma("unroll")                                                   \
    for (int h_=0; h_<2; ++h_){                                         \
      async16(&lds[base_ +        h_*2048 + t*8], aS[h_] + aoff_);      \
      async16(&lds[base_ + 4096 + h_*2048 + t*8], bS[h_] + boff_);      \
      async16(&lds[base_ + 8192 + h_*2048 + t*8], bS[h_] + BT_ELEMS + boff_); \
    } }while(0)

  STAGE(0, ks0);
  int buf = 0;
  for (int it = 0; it < 81; ++it){
    __syncthreads();
    if (it < 80) STAGE(buf^1, ks0 + it + 1);
    int base = buf*12288;
    short8 af[4], bh[4], bl[4];
    #pragma unroll
    for (int i=0;i<4;++i){
      af[i] = *(const short8*)&lds[base + roA[i]];
      bh[i] = *(const short8*)&lds[base + 4096 + roB[i]];
      bl[i] = *(const short8*)&lds[base + 8192 + roB[i]];
    }
    #pragma unroll
    for (int i=0;i<4;++i)
      #pragma unroll
      for (int j=0;j<4;++j){
        acc[i][j] = mfma_f16(af[i], bh[j], acc[i][j]);
        acc[i][j] = mfma_f16(af[i], bl[j], acc[i][j]);
      }
    buf ^= 1;
  }

  const int qm = (w >> 1)*64, qn = (w & 1)*64;
  #pragma unroll
  for (int i=0;i<4;++i){
    int gm = m0 + qm + i*16 + ((lane >> 4) << 2);
    #pragma unroll
    for (int j=0;j<4;++j){
      int gn = n0 + qn + j*16 + (lane & 15);
      #pragma unroll
      for (int rr=0;rr<4;++rr)
        atomicAdd(&out[(size_t)(gm + rr)*256 + gn], acc[i][j][rr]);
    }
  }
}

// ---------------- K3: fused squash(c2out)->pc  +  s1 partials ----------------
// block = 16 n x 16 b. n0 16-aligned -> one pixel (6x6 grid: 36 rows/batch),
// contiguous 128-oc slice.
__global__ __launch_bounds__(256) void s1pc_kernel(const float* __restrict__ c2out,
    const float* __restrict__ b2, float* __restrict__ pc,
    const float* __restrict__ Wm, float* __restrict__ s1){
  __shared__ float pcl[2048]; // [16 b][16 n][8 i]
  int t = threadIdx.x;
  int n0 = blockIdx.x * 16, b0 = blockIdx.y * 16;
  int pix = n0 >> 5, oc0 = (n0 & 31) * 8;
  {
    int bl = t >> 4, part = t & 15;
    const float* s = c2out + ((size_t)((b0 + bl)*36 + pix))*256 + oc0 + part*8;
    float v[8], sq = 0.f;
    #pragma unroll
    for (int e=0;e<8;++e){
      float x = fmaxf(s[e] + b2[oc0 + part*8 + e], 0.f);
      v[e] = x; sq += x*x;
    }
    float fac = sq / ((1.f + sq) * sqrtf(sq + EPS));
    float* o = pc + ((size_t)(b0 + bl)*1152 + n0 + part)*8;
    float* l = &pcl[(bl*16 + part)*8];
    #pragma unroll
    for (int e=0;e<8;++e){ float y = v[e]*fac; o[e] = y; l[e] = y; }
  }
  __syncthreads();
  for (int r = 0; r < 10; ++r){
    int item = r*256 + t;               // (b_local, cj)
    int bl = item / 160, cj = item - bl*160;
    float s1a = 0.f;
    const float* pb = &pcl[bl*128];
    #pragma unroll 4
    for (int nl = 0; nl < 16; ++nl){
      const float4* wp = (const float4*)&Wm[((size_t)(n0 + nl)*160 + cj)*8];
      float4 w0 = wp[0], w1 = wp[1];
      const float4* pp = (const float4*)&pb[nl*8];
      float4 p0 = pp[0], p1 = pp[1];
      s1a += w0.x*p0.x + w0.y*p0.y + w0.z*p0.z + w0.w*p0.w
           + w1.x*p1.x + w1.y*p1.y + w1.z*p1.z + w1.w*p1.w;
    }
    atomicAdd(&s1[(b0 + bl)*160 + cj], s1a);
  }
}

// ---------------- K4: fused routing v2: 32 n x 16 b per block ----------------
// pass1 thread=(nl,c) over 2 b-chunks; pass3 thread=(nl-half,cj) -> W traffic
// ~280 MB total (half of R7). No LDS atomics anywhere.
__global__ __launch_bounds__(320) void routing2(const float* __restrict__ pc,
    const float* __restrict__ Wm, const float* __restrict__ s1, float* __restrict__ s2){
  __shared__ float pcl[32][128];    // [nl][b*8+i]
  __shared__ float v1l[16][160];
  __shared__ float facl[160];
  __shared__ float c2l[32][10][16]; // [nl][c][b]: uv, then softmax'd c2
  const int t = threadIdx.x;
  const int n0 = blockIdx.x*32, b0 = blockIdx.y*16;

  for (int f = t; f < 4096; f += 320){
    int nl = f >> 7, rem = f & 127;
    pcl[nl][rem] = pc[((size_t)(b0 + (rem >> 3))*1152 + n0 + nl)*8 + (rem & 7)];
  }
  if (t < 160){
    int b = t/10, c = t - (t/10)*10;
    const float* s = s1 + (size_t)(b0 + b)*160 + c*16;
    float sq = 0.f;
    #pragma unroll
    for (int j=0;j<16;++j){ float v = s[j]*0.1f; sq += v*v; }
    facl[t] = 0.1f * sq / ((1.f + sq) * sqrtf(sq + EPS));
  }
  __syncthreads();
  for (int f = t; f < 2560; f += 320){
    int b = f / 160, cj = f - b*160;
    v1l[b][cj] = s1[(size_t)(b0 + b)*160 + cj] * facl[b*10 + (cj >> 4)];
  }
  __syncthreads();

  // ---- pass 1: uv.  thread = (nl, c), two chunks of 8 batches ----
  {
    const int nl = t / 10, c = t - (t/10)*10;
    const float* wrow = Wm + ((size_t)(n0 + nl)*160 + c*16)*8;
    #pragma unroll
    for (int g = 0; g < 2; ++g){
      float pcr[64];
      #pragma unroll
      for (int u = 0; u < 16; ++u)
        ((float4*)pcr)[u] = ((const float4*)&pcl[nl][g*64])[u];
      float uv[8];
      #pragma unroll
      for (int b=0;b<8;++b) uv[b] = 0.f;
      #pragma unroll
      for (int j = 0; j < 16; ++j){
        float4 w0 = ((const float4*)wrow)[j*2], w1 = ((const float4*)wrow)[j*2+1];
        #pragma unroll
        for (int b=0;b<8;++b){
          float tj = w0.x*pcr[b*8+0] + w0.y*pcr[b*8+1] + w0.z*pcr[b*8+2] + w0.w*pcr[b*8+3]
                   + w1.x*pcr[b*8+4] + w1.y*pcr[b*8+5] + w1.z*pcr[b*8+6] + w1.w*pcr[b*8+7];
          uv[b] = fmaf(tj, v1l[g*8+b][c*16 + j], uv[b]);
        }
      }
      #pragma unroll
      for (int b=0;b<8;++b) c2l[nl][c][g*8+b] = uv[b];
    }
  }
  __syncthreads();

  // ---- softmax over c: 512 (nl,b) items ----
  for (int idx = t; idx < 512; idx += 320){
    int snl = idx >> 4, sb = idx & 15;
    float mx = c2l[snl][0][sb];
    #pragma unroll
    for (int cc=1;cc<10;++cc) mx = fmaxf(mx, c2l[snl][cc][sb]);
    float e[10], sum = 0.f;
    #pragma unroll
    for (int cc=0;cc<10;++cc){ e[cc] = expf(c2l[snl][cc][sb] - mx); sum += e[cc]; }
    float inv = 1.f/sum;
    #pragma unroll
    for (int cc=0;cc<10;++cc) c2l[snl][cc][sb] = e[cc]*inv;
  }
  __syncthreads();

  // ---- pass 3: s2.  thread = (nl-half g, cj); 16 b-accumulators in regs ----
  {
    const int g = t / 160, cj = t - (t/160)*160;
    const int c = cj >> 4;
    float acc[16];
    #pragma unroll
    for (int b=0;b<16;++b) acc[b] = 0.f;
    for (int nn = 0; nn < 16; ++nn){
      int nl = g*16 + nn;
      const float4* wp = (const float4*)&Wm[((size_t)(n0 + nl)*160 + cj)*8];
      float4 w0 = wp[0], w1 = wp[1];
      #pragma unroll
      for (int b=0;b<16;++b){
        const float4* pp = (const float4*)&pcl[nl][b*8];
        float4 p0 = pp[0], p1 = pp[1];
        float uh = w0.x*p0.x + w0.y*p0.y + w0.z*p0.z + w0.w*p0.w
                 + w1.x*p1.x + w1.y*p1.y + w1.z*p1.z + w1.w*p1.w;
        acc[b] = fmaf(c2l[nl][c][b], uh, acc[b]);
      }
    }
    #pragma unroll
    for (int b=0;b<16;++b)
      atomicAdd(&s2[(size_t)(b0 + b)*160 + cj], acc[b]);
  }
}

// ---------------- K5: v2, norms, argmax + dec1 (one-hot: K=16) ----------------
__global__ __launch_bounds__(128) void final_dec1(const float* __restrict__ s2,
    const int* __restrict__ target, const float* __restrict__ d1w,
    const float* __restrict__ d1b, float* __restrict__ out_norm,
    float* __restrict__ out_pred, float* __restrict__ h1){
  __shared__ float v2t[16];
  __shared__ float nrm[10];
  int b = blockIdx.x, t = threadIdx.x;
  int tg = target[b];
  if (t < 10){
    const float* s = s2 + b*160 + t*16;
    float x[16], sq = 0.f;
    #pragma unroll
    for (int j=0;j<16;++j){ x[j] = s[j]; sq += x[j]*x[j]; }
    float fac = sq / ((1.f + sq) * sqrtf(sq + EPS));
    float n2 = 0.f;
    #pragma unroll
    for (int j=0;j<16;++j){
      float v = x[j]*fac;
      if (t == tg) v2t[j] = v;
      n2 += v*v;
    }
    float nr = sqrtf(n2 + EPS);
    nrm[t] = nr;
    out_norm[b*10 + t] = nr;
  }
  __syncthreads();
  if (t == 0){
    int am = 0; float bv = nrm[0];
    #pragma unroll
    for (int c=1;c<10;++c) if (nrm[c] > bv){ bv = nrm[c]; am = c; }
    out_pred[b] = (float)am;
  }
  float v[16];
  #pragma unroll
  for (int j=0;j<16;++j) v[j] = v2t[j];
  #pragma unroll
  for (int rr = 0; rr < 4; ++rr){
    int n = t + rr*128;
    float acc = d1b[n];
    #pragma unroll
    for (int j=0;j<16;++j) acc = fmaf(v[j], d1w[(size_t)(tg*16 + j)*512 + n], acc);
    h1[(size_t)b*512 + n] = fmaxf(acc, 0.f);
  }
}

// ---------------- decoder GEMMs (M=256 fixed) ----------------
__global__ __launch_bounds__(256) void dec_gemm(const float* __restrict__ A,
    const float* __restrict__ B, const float* __restrict__ bias, float* __restrict__ C,
    int K, int N, int act){
  int t = threadIdx.x;
  int n = blockIdx.x*64 + (t & 63);
  int m = blockIdx.y*4 + (t >> 6);
  if (n >= N) return;
  float acc = 0.f;
  const float* a = A + (size_t)m*K;
  const float* bp = B + n;
  #pragma unroll 8
  for (int k = 0; k < K; ++k) acc = fmaf(a[k], bp[(size_t)k*N], acc);
  acc += bias[n];
  if (act == 0) acc = fmaxf(acc, 0.f);
  else acc = 1.f/(1.f + expf(-acc));
  C[(size_t)m*N + n] = acc;
}

extern "C" void kernel_launch(void* const* d_in, const int* in_sizes, int n_in,
                              void* d_out, int out_size, void* d_ws, size_t ws_size,
                              hipStream_t stream) {
  const float* image   = (const float*)d_in[0];
  const int*   target  = (const int*)d_in[1];
  const float* conv1_w = (const float*)d_in[2];
  const float* conv1_b = (const float*)d_in[3];
  const float* conv2_w = (const float*)d_in[4];
  const float* conv2_b = (const float*)d_in[5];
  const float* Wm      = (const float*)d_in[6];
  const float* d1_w    = (const float*)d_in[7];
  const float* d1_b    = (const float*)d_in[8];
  const float* d2_w    = (const float*)d_in[9];
  const float* d2_b    = (const float*)d_in[10];
  const float* d3_w    = (const float*)d_in[11];
  const float* d3_b    = (const float*)d_in[12];

  char* ws = (char*)d_ws;
  unsigned short* in1h = (unsigned short*)(ws);               // fp16, 52428800 B
  unsigned short* BTh  = (unsigned short*)(ws + 52428800);    // fp16 hi; +BT_ELEMS: lo
  float* c2out  = (float*)(ws + 73662464);                    // 9437184 B
  float* pc     = (float*)(ws + 83099648);                    // 9437184 B
  float* s1     = (float*)(ws + 92536832);                    // 163840 B
  float* s2     = (float*)(ws + 92700672);                    // 163840 B (contiguous after s1)
  float* h1     = (float*)(ws + 92864512);                    // 524288 B
  float* h2     = (float*)(ws + 93388800);                    // 1048576 B

  float* out_norm = (float*)d_out;            // 2560
  float* out_pred = out_norm + 2560;          // 256
  float* dec      = out_norm + 2816;          // 200704

  prep_kernel<<<dim3(6416),256,0,stream>>>(conv2_w, BTh, BTh + BT_ELEMS, c2out,
                                           image, conv1_w, conv1_b, in1h, s1);
  conv2_mfma<<<dim3(2,72,8),256,0,stream>>>(in1h, BTh, c2out);
  s1pc_kernel<<<dim3(72,16),256,0,stream>>>(c2out, conv2_b, pc, Wm, s1);
  routing2<<<dim3(36,16),320,0,stream>>>(pc, Wm, s1, s2);
  final_dec1<<<dim3(256),128,0,stream>>>(s2, target, d1_w, d1_b, out_norm, out_pred, h1);
  dec_gemm<<<dim3(16,64),256,0,stream>>>(h1, d2_w, d2_b, h2, 512, 1024, 0);
  dec_gemm<<<dim3(13,64),256,0,stream>>>(h2, d3_w, d3_b, dec, 1024, 784, 1);
}

// Round 10
// 625.841 us; speedup vs baseline: 1.1026x; 1.1026x over previous
//
#include <hip/hip_runtime.h>
#include <math.h>

#define EPS 1e-7f
#define IN1_ELEMS 26214400   // 256*20*20*256 (fp16 elements, single plane)
#define BT_ELEMS  5308416    // 256*20736 (per fp16 plane)

typedef float fvec4 __attribute__((ext_vector_type(4)));
typedef short short8 __attribute__((ext_vector_type(8)));
typedef _Float16 half8 __attribute__((ext_vector_type(8)));

__device__ inline unsigned short f2h(float f){
  _Float16 h = (_Float16)f;
  return __builtin_bit_cast(unsigned short, h);
}
__device__ inline float h2f(unsigned short u){
  return (float)__builtin_bit_cast(_Float16, u);
}
__device__ inline void async16(unsigned short* dst, const unsigned short* src){
  __builtin_amdgcn_global_load_lds((const __attribute__((address_space(1))) void*)src,
                                   (__attribute__((address_space(3))) void*)dst, 16, 0, 0);
}
__device__ inline fvec4 mfma_f16(short8 a, short8 b, fvec4 c){
  return __builtin_amdgcn_mfma_f32_16x16x32_f16(
      __builtin_bit_cast(half8, a), __builtin_bit_cast(half8, b), c, 0, 0, 0);
}

// ---------------- K0: prep = wt (B split, x64) + conv1 (fp16 x 2^-6) + zeroing -------
__global__ __launch_bounds__(256) void prep_kernel(const float* __restrict__ w2,
    unsigned short* __restrict__ BTh, unsigned short* __restrict__ BTl,
    float* __restrict__ c2out,
    const float* __restrict__ img, const float* __restrict__ w1,
    const float* __restrict__ b1, unsigned short* __restrict__ outh,
    float* __restrict__ s1s2){
  const int bid = blockIdx.x;
  const int t = threadIdx.x;
  if (bid < 1296){
    __shared__ float tile[64][65];
    int k0 = (bid % 324) * 64, oc0 = (bid / 324) * 64;
    for (int g = bid*256 + t; g < 2359296; g += 1296*256) c2out[g] = 0.f;
    #pragma unroll
    for (int p = 0; p < 16; ++p){
      int f = p*256 + t;
      int kr = f >> 6, cc = f & 63;
      tile[kr][cc] = w2[(size_t)(k0 + kr)*256 + oc0 + cc];
    }
    __syncthreads();
    #pragma unroll
    for (int p = 0; p < 16; ++p){
      int f = p*256 + t;
      int ocr = f >> 6, kc = f & 63;
      float v = tile[kc][ocr] * 64.f;
      unsigned short h = f2h(v);
      size_t idx = (size_t)(oc0 + ocr)*20736 + k0 + kc;
      BTh[idx] = h;
      BTl[idx] = f2h(v - h2f(h));
    }
  } else {
    const int cid = bid - 1296;
    if (cid < 320) s1s2[cid*256 + t] = 0.f;
    __shared__ float sim[252];
    int oh = cid % 20, b = cid / 20;
    if (t < 252) sim[t] = img[((size_t)b*28 + oh + t/28)*28 + (t%28)];
    __syncthreads();
    float acc[20];
    #pragma unroll
    for (int i = 0; i < 20; ++i) acc[i] = 0.f;
    #pragma unroll
    for (int kh = 0; kh < 9; ++kh){
      float im[28];
      #pragma unroll
      for (int c = 0; c < 28; ++c) im[c] = sim[kh*28 + c];
      #pragma unroll
      for (int kw = 0; kw < 9; ++kw){
        float wv = w1[(kh*9 + kw)*256 + t];
        #pragma unroll
        for (int ow = 0; ow < 20; ++ow) acc[ow] = fmaf(im[ow + kw], wv, acc[ow]);
      }
    }
    float bv = b1[t];
    size_t base = ((size_t)(b*20 + oh))*20*256 + t;
    #pragma unroll
    for (int ow = 0; ow < 20; ++ow){
      float v = fmaxf(acc[ow] + bv, 0.f);
      outh[base + ow*256] = f2h(v * 0.015625f);   // x 2^-6
    }
  }
}

// ---------------- K2: conv2 implicit GEMM, fp16 2-pass MFMA, splitK=12 ----------------
__global__ __launch_bounds__(256) void conv2_mfma(const unsigned short* __restrict__ in1h,
    const unsigned short* __restrict__ BTh, float* __restrict__ out){
  __shared__ __align__(16) unsigned short lds[24576]; // 2 bufs x (A|Bh|Bl 4096 shorts)
  const int t = threadIdx.x;
  const int lane = t & 63, w = t >> 6;
  const int m0 = blockIdx.y * 128, n0 = blockIdx.x * 128;
  const int rowA = t >> 2, q = (t & 3) ^ ((t >> 3) & 3);

  const unsigned short* aS[2];
  const unsigned short* bS[2];
  #pragma unroll
  for (int h = 0; h < 2; ++h){
    int m = m0 + h*64 + rowA;
    int bb = m / 36, s = m - bb*36, oh = s / 6, ow = s - oh*6;
    aS[h] = in1h + ((size_t)((bb*20 + 2*oh)*20 + 2*ow))*256 + q*8;
    int n = n0 + h*64 + rowA;
    bS[h] = BTh + (size_t)n*20736 + q*8;
  }

  const int r = lane & 15;
  const int p = (lane >> 4) ^ ((lane >> 1) & 3);
  int roA[4], roB[4];
  #pragma unroll
  for (int i=0;i<4;++i){
    roA[i] = ((w >> 1)*64 + i*16 + r)*32 + p*8;
    roB[i] = ((w & 1)*64  + i*16 + r)*32 + p*8;
  }

  fvec4 acc[4][4];
  #pragma unroll
  for (int i=0;i<4;++i)
    #pragma unroll
    for (int j=0;j<4;++j) acc[i][j] = (fvec4){0.f,0.f,0.f,0.f};

  const int ks0 = blockIdx.z * 54;

  #define STAGE(BUF, KS) do{                                            \
    int kk_ = (KS) >> 3, kh_ = kk_/9, kw_ = kk_ - kh_*9;                \
    int aoff_ = (kh_*20 + kw_)*256 + ((KS) & 7)*32;                     \
    int boff_ = (KS)*32;                                                \
    int base_ = (BUF)*12288;                                            \
    _Pragma("unroll")                                                   \
    for (int h_=0; h_<2; ++h_){                                         \
      async16(&lds[base_ +        h_*2048 + t*8], aS[h_] + aoff_);      \
      async16(&lds[base_ + 4096 + h_*2048 + t*8], bS[h_] + boff_);      \
      async16(&lds[base_ + 8192 + h_*2048 + t*8], bS[h_] + BT_ELEMS + boff_); \
    } }while(0)

  STAGE(0, ks0);
  int buf = 0;
  for (int it = 0; it < 54; ++it){
    __syncthreads();
    if (it < 53) STAGE(buf^1, ks0 + it + 1);
    int base = buf*12288;
    short8 af[4], bh[4], bl[4];
    #pragma unroll
    for (int i=0;i<4;++i){
      af[i] = *(const short8*)&lds[base + roA[i]];
      bh[i] = *(const short8*)&lds[base + 4096 + roB[i]];
      bl[i] = *(const short8*)&lds[base + 8192 + roB[i]];
    }
    #pragma unroll
    for (int i=0;i<4;++i)
      #pragma unroll
      for (int j=0;j<4;++j){
        acc[i][j] = mfma_f16(af[i], bh[j], acc[i][j]);
        acc[i][j] = mfma_f16(af[i], bl[j], acc[i][j]);
      }
    buf ^= 1;
  }

  const int qm = (w >> 1)*64, qn = (w & 1)*64;
  #pragma unroll
  for (int i=0;i<4;++i){
    int gm = m0 + qm + i*16 + ((lane >> 4) << 2);
    #pragma unroll
    for (int j=0;j<4;++j){
      int gn = n0 + qn + j*16 + (lane & 15);
      #pragma unroll
      for (int rr=0;rr<4;++rr)
        atomicAdd(&out[(size_t)(gm + rr)*256 + gn], acc[i][j][rr]);
    }
  }
}

// ---------------- K3: fused squash(c2out)->pc  +  s1 partials ----------------
__global__ __launch_bounds__(256) void s1pc_kernel(const float* __restrict__ c2out,
    const float* __restrict__ b2, float* __restrict__ pc,
    const float* __restrict__ Wm, float* __restrict__ s1){
  __shared__ float pcl[2048]; // [16 b][16 n][8 i]
  int t = threadIdx.x;
  int n0 = blockIdx.x * 16, b0 = blockIdx.y * 16;
  int pix = n0 >> 5, oc0 = (n0 & 31) * 8;
  {
    int bl = t >> 4, part = t & 15;
    const float* s = c2out + ((size_t)((b0 + bl)*36 + pix))*256 + oc0 + part*8;
    float v[8], sq = 0.f;
    #pragma unroll
    for (int e=0;e<8;++e){
      float x = fmaxf(s[e] + b2[oc0 + part*8 + e], 0.f);
      v[e] = x; sq += x*x;
    }
    float fac = sq / ((1.f + sq) * sqrtf(sq + EPS));
    float* o = pc + ((size_t)(b0 + bl)*1152 + n0 + part)*8;
    float* l = &pcl[(bl*16 + part)*8];
    #pragma unroll
    for (int e=0;e<8;++e){ float y = v[e]*fac; o[e] = y; l[e] = y; }
  }
  __syncthreads();
  for (int r = 0; r < 10; ++r){
    int item = r*256 + t;               // (b_local, cj)
    int bl = item / 160, cj = item - bl*160;
    float s1a = 0.f;
    const float* pb = &pcl[bl*128];
    #pragma unroll 4
    for (int nl = 0; nl < 16; ++nl){
      const float4* wp = (const float4*)&Wm[((size_t)(n0 + nl)*160 + cj)*8];
      float4 w0 = wp[0], w1 = wp[1];
      const float4* pp = (const float4*)&pb[nl*8];
      float4 p0 = pp[0], p1 = pp[1];
      s1a += w0.x*p0.x + w0.y*p0.y + w0.z*p0.z + w0.w*p0.w
           + w1.x*p1.x + w1.y*p1.y + w1.z*p1.z + w1.w*p1.w;
    }
    atomicAdd(&s1[(b0 + bl)*160 + cj], s1a);
  }
}

// ---------------- K4: fused routing (R6 measured-good version: 32 n x 8 b) -----------
__global__ __launch_bounds__(320) void routing2(const float* __restrict__ pc,
    const float* __restrict__ Wm, const float* __restrict__ s1, float* __restrict__ s2){
  __shared__ float pcl[32][64];     // [nl][b*8+i]
  __shared__ float v1l[8][160];
  __shared__ float facl[80];
  __shared__ float c2l[32][10][8];  // [nl][c][b]: uv, then softmax'd c2
  const int t = threadIdx.x;
  const int n0 = blockIdx.x*32, b0 = blockIdx.y*8;

  for (int f = t; f < 2048; f += 320){
    int b = f >> 8, rem = f & 255;            // rem = nl*8+i
    pcl[rem >> 3][b*8 + (rem & 7)] =
        pc[((size_t)(b0 + b)*1152 + n0 + (rem >> 3))*8 + (rem & 7)];
  }
  if (t < 80){
    int b = t/10, c = t - (t/10)*10;
    const float* s = s1 + (size_t)(b0 + b)*160 + c*16;
    float sq = 0.f;
    #pragma unroll
    for (int j=0;j<16;++j){ float v = s[j]*0.1f; sq += v*v; }
    facl[t] = 0.1f * sq / ((1.f + sq) * sqrtf(sq + EPS));
  }
  __syncthreads();
  for (int f = t; f < 1280; f += 320){
    int b = f / 160, cj = f - b*160;
    v1l[b][cj] = s1[(size_t)(b0 + b)*160 + cj] * facl[b*10 + (cj >> 4)];
  }
  __syncthreads();

  // ---- pass 1: uv.  thread = (nl, c) ----
  {
    const int nl = t / 10, c = t - (t/10)*10;
    float pcr[64];
    #pragma unroll
    for (int u = 0; u < 16; ++u) ((float4*)pcr)[u] = ((const float4*)&pcl[nl][0])[u];
    const float* wrow = Wm + ((size_t)(n0 + nl)*160 + c*16)*8;
    float uv[8];
    #pragma unroll
    for (int b=0;b<8;++b) uv[b] = 0.f;
    #pragma unroll
    for (int j = 0; j < 16; ++j){
      float4 w0 = ((const float4*)wrow)[j*2], w1 = ((const float4*)wrow)[j*2+1];
      #pragma unroll
      for (int b=0;b<8;++b){
        float tj = w0.x*pcr[b*8+0] + w0.y*pcr[b*8+1] + w0.z*pcr[b*8+2] + w0.w*pcr[b*8+3]
                 + w1.x*pcr[b*8+4] + w1.y*pcr[b*8+5] + w1.z*pcr[b*8+6] + w1.w*pcr[b*8+7];
        uv[b] = fmaf(tj, v1l[b][c*16 + j], uv[b]);
      }
    }
    #pragma unroll
    for (int b=0;b<8;++b) c2l[nl][c][b] = uv[b];
  }
  __syncthreads();

  // ---- softmax over c: thread = (nl, b) ----
  if (t < 256){
    int snl = t >> 3, sb = t & 7;
    float mx = c2l[snl][0][sb];
    #pragma unroll
    for (int cc=1;cc<10;++cc) mx = fmaxf(mx, c2l[snl][cc][sb]);
    float e[10], sum = 0.f;
    #pragma unroll
    for (int cc=0;cc<10;++cc){ e[cc] = expf(c2l[snl][cc][sb] - mx); sum += e[cc]; }
    float inv = 1.f/sum;
    #pragma unroll
    for (int cc=0;cc<10;++cc) c2l[snl][cc][sb] = e[cc]*inv;
  }
  __syncthreads();

  // ---- pass 3: s2.  thread = (b-quad g, cj); owns 4 accumulators ----
  {
    const int g = t / 160, cj = t - g*160;   // g in {0,1}
    const int c = cj >> 4;
    float acc0 = 0.f, acc1 = 0.f, acc2 = 0.f, acc3 = 0.f;
    for (int nl = 0; nl < 32; ++nl){
      const float4* wp = (const float4*)&Wm[((size_t)(n0 + nl)*160 + cj)*8];
      float4 w0 = wp[0], w1 = wp[1];
      const float* pb = &pcl[nl][g*32];
      const float* cc = &c2l[nl][c][g*4];
      float4 p0, p1;
      p0 = ((const float4*)pb)[0]; p1 = ((const float4*)pb)[1];
      acc0 = fmaf(cc[0], w0.x*p0.x + w0.y*p0.y + w0.z*p0.z + w0.w*p0.w
                       + w1.x*p1.x + w1.y*p1.y + w1.z*p1.z + w1.w*p1.w, acc0);
      p0 = ((const float4*)pb)[2]; p1 = ((const float4*)pb)[3];
      acc1 = fmaf(cc[1], w0.x*p0.x + w0.y*p0.y + w0.z*p0.z + w0.w*p0.w
                       + w1.x*p1.x + w1.y*p1.y + w1.z*p1.z + w1.w*p1.w, acc1);
      p0 = ((const float4*)pb)[4]; p1 = ((const float4*)pb)[5];
      acc2 = fmaf(cc[2], w0.x*p0.x + w0.y*p0.y + w0.z*p0.z + w0.w*p0.w
                       + w1.x*p1.x + w1.y*p1.y + w1.z*p1.z + w1.w*p1.w, acc2);
      p0 = ((const float4*)pb)[6]; p1 = ((const float4*)pb)[7];
      acc3 = fmaf(cc[3], w0.x*p0.x + w0.y*p0.y + w0.z*p0.z + w0.w*p0.w
                       + w1.x*p1.x + w1.y*p1.y + w1.z*p1.z + w1.w*p1.w, acc3);
    }
    atomicAdd(&s2[(size_t)(b0 + g*4 + 0)*160 + cj], acc0);
    atomicAdd(&s2[(size_t)(b0 + g*4 + 1)*160 + cj], acc1);
    atomicAdd(&s2[(size_t)(b0 + g*4 + 2)*160 + cj], acc2);
    atomicAdd(&s2[(size_t)(b0 + g*4 + 3)*160 + cj], acc3);
  }
}

// ---------------- K5: v2, norms, argmax + dec1 (one-hot: K=16) ----------------
__global__ __launch_bounds__(128) void final_dec1(const float* __restrict__ s2,
    const int* __restrict__ target, const float* __restrict__ d1w,
    const float* __restrict__ d1b, float* __restrict__ out_norm,
    float* __restrict__ out_pred, float* __restrict__ h1){
  __shared__ float v2t[16];
  __shared__ float nrm[10];
  int b = blockIdx.x, t = threadIdx.x;
  int tg = target[b];
  if (t < 10){
    const float* s = s2 + b*160 + t*16;
    float x[16], sq = 0.f;
    #pragma unroll
    for (int j=0;j<16;++j){ x[j] = s[j]; sq += x[j]*x[j]; }
    float fac = sq / ((1.f + sq) * sqrtf(sq + EPS));
    float n2 = 0.f;
    #pragma unroll
    for (int j=0;j<16;++j){
      float v = x[j]*fac;
      if (t == tg) v2t[j] = v;
      n2 += v*v;
    }
    float nr = sqrtf(n2 + EPS);
    nrm[t] = nr;
    out_norm[b*10 + t] = nr;
  }
  __syncthreads();
  if (t == 0){
    int am = 0; float bv = nrm[0];
    #pragma unroll
    for (int c=1;c<10;++c) if (nrm[c] > bv){ bv = nrm[c]; am = c; }
    out_pred[b] = (float)am;
  }
  float v[16];
  #pragma unroll
  for (int j=0;j<16;++j) v[j] = v2t[j];
  #pragma unroll
  for (int rr = 0; rr < 4; ++rr){
    int n = t + rr*128;
    float acc = d1b[n];
    #pragma unroll
    for (int j=0;j<16;++j) acc = fmaf(v[j], d1w[(size_t)(tg*16 + j)*512 + n], acc);
    h1[(size_t)b*512 + n] = fmaxf(acc, 0.f);
  }
}

// ---------------- decoder GEMMs (M=256 fixed) ----------------
__global__ __launch_bounds__(256) void dec_gemm(const float* __restrict__ A,
    const float* __restrict__ B, const float* __restrict__ bias, float* __restrict__ C,
    int K, int N, int act){
  int t = threadIdx.x;
  int n = blockIdx.x*64 + (t & 63);
  int m = blockIdx.y*4 + (t >> 6);
  if (n >= N) return;
  float acc = 0.f;
  const float* a = A + (size_t)m*K;
  const float* bp = B + n;
  #pragma unroll 8
  for (int k = 0; k < K; ++k) acc = fmaf(a[k], bp[(size_t)k*N], acc);
  acc += bias[n];
  if (act == 0) acc = fmaxf(acc, 0.f);
  else acc = 1.f/(1.f + expf(-acc));
  C[(size_t)m*N + n] = acc;
}

extern "C" void kernel_launch(void* const* d_in, const int* in_sizes, int n_in,
                              void* d_out, int out_size, void* d_ws, size_t ws_size,
                              hipStream_t stream) {
  const float* image   = (const float*)d_in[0];
  const int*   target  = (const int*)d_in[1];
  const float* conv1_w = (const float*)d_in[2];
  const float* conv1_b = (const float*)d_in[3];
  const float* conv2_w = (const float*)d_in[4];
  const float* conv2_b = (const float*)d_in[5];
  const float* Wm      = (const float*)d_in[6];
  const float* d1_w    = (const float*)d_in[7];
  const float* d1_b    = (const float*)d_in[8];
  const float* d2_w    = (const float*)d_in[9];
  const float* d2_b    = (const float*)d_in[10];
  const float* d3_w    = (const float*)d_in[11];
  const float* d3_b    = (const float*)d_in[12];

  char* ws = (char*)d_ws;
  unsigned short* in1h = (unsigned short*)(ws);               // fp16, 52428800 B
  unsigned short* BTh  = (unsigned short*)(ws + 52428800);    // fp16 hi; +BT_ELEMS: lo
  float* c2out  = (float*)(ws + 73662464);                    // 9437184 B
  float* pc     = (float*)(ws + 83099648);                    // 9437184 B
  float* s1     = (float*)(ws + 92536832);                    // 163840 B
  float* s2     = (float*)(ws + 92700672);                    // 163840 B (contiguous after s1)
  float* h1     = (float*)(ws + 92864512);                    // 524288 B
  float* h2     = (float*)(ws + 93388800);                    // 1048576 B

  float* out_norm = (float*)d_out;            // 2560
  float* out_pred = out_norm + 2560;          // 256
  float* dec      = out_norm + 2816;          // 200704

  prep_kernel<<<dim3(6416),256,0,stream>>>(conv2_w, BTh, BTh + BT_ELEMS, c2out,
                                           image, conv1_w, conv1_b, in1h, s1);
  conv2_mfma<<<dim3(2,72,12),256,0,stream>>>(in1h, BTh, c2out);
  s1pc_kernel<<<dim3(72,16),256,0,stream>>>(c2out, conv2_b, pc, Wm, s1);
  routing2<<<dim3(36,32),320,0,stream>>>(pc, Wm, s1, s2);
  final_dec1<<<dim3(256),128,0,stream>>>(s2, target, d1_w, d1_b, out_norm, out_pred, h1);
  dec_gemm<<<dim3(16,64),256,0,stream>>>(h1, d2_w, d2_b, h2, 512, 1024, 0);
  dec_gemm<<<dim3(13,64),256,0,stream>>>(h2, d3_w, d3_b, dec, 1024, 784, 1);
}